// Round 4
// baseline (72.970 us; speedup 1.0000x reference)
//
#include <hip/hip_runtime.h>
#include <math.h>

// Problem constants (static config)
#define NB 1024     // batches
#define NS 64       // steps S
#define NT 63       // T = S-1
#define NV 192      // N = S*3 variables
#define BW 7        // band half-width+1 (fallback kernel)
#define NC 314      // constraint rows (fallback kernel)
#define NG 16       // 1024/64 wave-groups

// ws regions (per group, per lane): lane-transposed layout slot*64+lane
#define IN_SLOTS 328   // coeffs 0..191, rhs 192..255, steps 256..318, iv 320..323
#define L_SLOTS  1536  // 8 per column (dinv, L1..L6, y) x 192
#define X_SLOTS  192
#define IN_COEF 0
#define IN_RHS  192
#define IN_STP  256
#define IN_IV   320

// ============================================================================
// K1: transpose inputs into lane-transposed ws layout. All global traffic
// coalesced; LDS tile 64x65 (odd stride -> conflict-free).
// ============================================================================
__global__ __launch_bounds__(1024, 1)
void ode_tin(const float* __restrict__ coeffs,
             const float* __restrict__ rhs,
             const float* __restrict__ steps,
             const float* __restrict__ iv_rhs,
             float* __restrict__ wsIn)
{
    const int g   = blockIdx.x;
    const int tid = threadIdx.x;
    __shared__ float tile[64 * 65];

    // ---- coeffs: 3 chunks of 64 slots ----
    for (int c = 0; c < 3; ++c) {
        for (int idx = tid; idx < 64 * 64; idx += 1024) {
            const int b = idx >> 6, i = idx & 63;
            tile[b * 65 + i] = coeffs[(size_t)g * 12288 + (size_t)b * 192 + c * 64 + i];
        }
        __syncthreads();
        for (int idx = tid; idx < 64 * 64; idx += 1024) {
            const int i = idx >> 6, l = idx & 63;
            wsIn[((size_t)g * IN_SLOTS + IN_COEF + c * 64 + i) * 64 + l] = tile[l * 65 + i];
        }
        __syncthreads();
    }
    // ---- rhs: 64 slots ----
    for (int idx = tid; idx < 64 * 64; idx += 1024) {
        const int b = idx >> 6, i = idx & 63;
        tile[b * 65 + i] = rhs[(size_t)g * 4096 + idx];
    }
    __syncthreads();
    for (int idx = tid; idx < 64 * 64; idx += 1024) {
        const int i = idx >> 6, l = idx & 63;
        wsIn[((size_t)g * IN_SLOTS + IN_RHS + i) * 64 + l] = tile[l * 65 + i];
    }
    __syncthreads();
    // ---- steps: 63 slots ----
    for (int idx = tid; idx < 64 * 63; idx += 1024) {
        const int b = idx / 63, i = idx - b * 63;
        tile[b * 65 + i] = steps[(size_t)g * 4032 + idx];
    }
    __syncthreads();
    for (int idx = tid; idx < 63 * 64; idx += 1024) {
        const int i = idx >> 6, l = idx & 63;
        wsIn[((size_t)g * IN_SLOTS + IN_STP + i) * 64 + l] = tile[l * 65 + i];
    }
    __syncthreads();
    // ---- iv: 4 slots ----
    for (int idx = tid; idx < 64 * 4; idx += 1024) {
        const int b = idx >> 2, i = idx & 3;
        tile[b * 65 + i] = iv_rhs[(size_t)g * 256 + idx];
    }
    __syncthreads();
    for (int idx = tid; idx < 4 * 64; idx += 1024) {
        const int i = idx >> 6, l = idx & 63;
        wsIn[((size_t)g * IN_SLOTS + IN_IV + i) * 64 + l] = tile[l * 65 + i];
    }
}

// ============================================================================
// K2: one THREAD per batch. Closed-form band columns; left-looking banded
// Cholesky (h=6) with register window; fused forward solve; back-substitution
// unrolled x3 with role rotation (depth-3 prefetch). ALL global accesses
// coalesced (lane-transposed ws). Separate __restrict__ regions -> no
// load/store aliasing waits.
// ============================================================================
__global__ __launch_bounds__(64, 1)
void ode_fused2(const float* __restrict__ wsIn,
                float* __restrict__ wsL,
                float* __restrict__ wsX)
{
    const int g = blockIdx.x;
    const int l = threadIdx.x;

    const float* __restrict__ inA = wsIn + (size_t)g * IN_SLOTS * 64 + l;
    float* __restrict__ lnA = wsL + (size_t)g * L_SLOTS * 64 + l;
    float* __restrict__ xA  = wsX + (size_t)g * X_SLOTS * 64 + l;

#define SLI(i) inA[(size_t)(i) * 64]
#define SL(i)  lnA[(size_t)(i) * 64]
#define SX(i)  xA[(size_t)(i) * 64]

    // ---- Cholesky window: W[p][k] = L[(j-p)+k][j-p], k >= p ----
    float W11 = 0, W12 = 0, W13 = 0, W14 = 0, W15 = 0, W16 = 0;
    float W22 = 0, W23 = 0, W24 = 0, W25 = 0, W26 = 0;
    float W33 = 0, W34 = 0, W35 = 0, W36 = 0;
    float W44 = 0, W45 = 0, W46 = 0;
    float W55 = 0, W56 = 0;
    float W66 = 0;
    float y1 = 0, y2 = 0, y3 = 0, y4 = 0, y5 = 0, y6 = 0;

#define CHOL_COL(j, b0, b1, b2, b3, b4, b5, b6, rvv)                           \
    {                                                                          \
        const float t0 = (b0) - (W11*W11 + W22*W22 + W33*W33 +                 \
                                 W44*W44 + W55*W55 + W66*W66);                 \
        const float dinv = rsqrtf(t0);                                         \
        const float u1 = (b1) - (W11*W12 + W22*W23 + W33*W34 +                 \
                                 W44*W45 + W55*W56);                           \
        const float u2 = (b2) - (W11*W13 + W22*W24 + W33*W35 + W44*W46);       \
        const float u3 = (b3) - (W11*W14 + W22*W25 + W33*W36);                 \
        const float u4 = (b4) - (W11*W15 + W22*W26);                           \
        const float u5 = (b5) - (W11*W16);                                     \
        const float u6 = (b6);                                                 \
        const float yj = ((rvv) - (W11*y1 + W22*y2 + W33*y3 +                  \
                                   W44*y4 + W55*y5 + W66*y6)) * dinv;          \
        const float n1 = u1*dinv, n2 = u2*dinv, n3 = u3*dinv;                  \
        const float n4 = u4*dinv, n5 = u5*dinv, n6 = u6*dinv;                  \
        SL((j)*8 + 0) = dinv; SL((j)*8 + 1) = n1;  SL((j)*8 + 2) = n2;         \
        SL((j)*8 + 3) = n3;   SL((j)*8 + 4) = n4;  SL((j)*8 + 5) = n5;         \
        SL((j)*8 + 6) = n6;   SL((j)*8 + 7) = yj;                              \
        W66 = W56;                                                             \
        W55 = W45; W56 = W46;                                                  \
        W44 = W34; W45 = W35; W46 = W36;                                       \
        W33 = W23; W34 = W24; W35 = W25; W36 = W26;                            \
        W22 = W12; W23 = W13; W24 = W14; W25 = W15; W26 = W16;                 \
        W11 = n1;  W12 = n2;  W13 = n3;  W14 = n4;  W15 = n5;  W16 = n6;       \
        y6 = y5; y5 = y4; y4 = y3; y3 = y2; y2 = y1; y1 = yj;                  \
    }

    // ---- iv rhs (coalesced) ----
    const float iv00 = SLI(IN_IV + 0);
    const float iv01 = SLI(IN_IV + 1);
    const float iv10 = SLI(IN_IV + 2);
    const float iv11 = SLI(IN_IV + 3);

    // ---- depth-3 input pipeline: stages a=t, b=t+1, c=t+2 ----
    float aC0 = SLI(IN_COEF + 0), aC1 = SLI(IN_COEF + 1), aC2 = SLI(IN_COEF + 2);
    float aR  = SLI(IN_RHS + 0);
    float bC0 = SLI(IN_COEF + 3), bC1 = SLI(IN_COEF + 4), bC2 = SLI(IN_COEF + 5);
    float bR  = SLI(IN_RHS + 1);
    float cC0 = SLI(IN_COEF + 6), cC1 = SLI(IN_COEF + 7), cC2 = SLI(IN_COEF + 8);
    float cR  = SLI(IN_RHS + 2);
    // steps chain: p=s_{t-1}, s=s_t, sn=s_{t+1}, q2=s_{t+2}, q3=s_{t+3}
    float p  = 0.f;
    float s  = SLI(IN_STP + 0);
    float sn = SLI(IN_STP + 1);
    float q2 = SLI(IN_STP + 2);
    float q3 = SLI(IN_STP + 3);

    for (int t = 0; t < NS; ++t) {
        // prefetch step t+3 (wave-uniform guards)
        float nC0 = 0, nC1 = 0, nC2 = 0, nR = 0, nq = 0;
        if (t + 3 < NS) {
            nC0 = SLI(IN_COEF + 3 * (t + 3));
            nC1 = SLI(IN_COEF + 3 * (t + 3) + 1);
            nC2 = SLI(IN_COEF + 3 * (t + 3) + 2);
            nR  = SLI(IN_RHS + t + 3);
        }
        if (t + 4 < NT) nq = SLI(IN_STP + t + 4);

        // boundary masks
        const float mS  = (t < NS - 1) ? 1.f : 0.f;
        const float mP  = (t >= 1)     ? 1.f : 0.f;
        const float mCN = (t < NS - 2) ? 1.f : 0.f;
        const float mC0 = (t >= 1 && t < NS - 1) ? 1.f : 0.f;
        const float rg  = (t < 2) ? 1.f : 0.f;
        const float ivA = (t == 0) ? iv00 : ((t == 1) ? iv10 : 0.f);
        const float ivB = (t == 0) ? iv01 : ((t == 1) ? iv11 : 0.f);

        // band columns of AtA for step t (closed form; verified rounds 1-3)
        const float s2 = s*s, s3 = s2*s, p2 = p*p, p3 = p2*p;
        const float gt = p + s;

        const float A0 = aC0*aC0 + rg + 2.f*(mS + mP);
        const float A1 = aC0*aC1 + s - p;
        const float A2 = aC0*aC2 + 0.5f*(s2 + p2);
        const float A3 = -2.f*mS;
        const float A4 = s;
        const float A5 = -0.5f*s2;

        const float B0 = aC1*aC1 + 3.f*(s2 + p2) + mCN + 1.f;
        const float B1 = aC1*aC2 + 1.5f*(s3 - p3);
        const float B2 = -s;
        const float B3 = -2.f*s2;
        const float B4 = s3 + (s + sn)*mCN;
        const float B6 = -mCN;

        const float Cv0 = aC2*aC2 + 1.25f*(s2*s2 + p2*p2) + gt*gt*mC0;
        const float Cv1 = -0.5f*s2;
        const float Cv2 = -s3 - gt*mC0;

        const float rv0 = aC0*aR + ivA;
        const float rv1 = aC1*aR + ivB;
        const float rv2 = aC2*aR;

        const int j0 = 3*t;
        CHOL_COL(j0 + 0, A0,  A1,  A2,  A3,  A4,  A5,  0.f, rv0);
        CHOL_COL(j0 + 1, B0,  B1,  B2,  B3,  B4,  0.f, B6,  rv1);
        CHOL_COL(j0 + 2, Cv0, Cv1, Cv2, 0.f, 0.f, 0.f, 0.f, rv2);

        // shift pipelines
        aC0 = bC0; aC1 = bC1; aC2 = bC2; aR = bR;
        bC0 = cC0; bC1 = cC1; bC2 = cC2; bR = cR;
        cC0 = nC0; cC1 = nC1; cC2 = nC2; cR = nR;
        p = s; s = sn; sn = q2; q2 = q3; q3 = nq;
    }

    // ---- back-substitution, unrolled x3 with role rotation (P/Q/R) ----
#define DECL8(P) float P##d = 0, P##1 = 0, P##2 = 0, P##3 = 0,                 \
                       P##4 = 0, P##5 = 0, P##6 = 0, P##y = 0;
#define LOAD8(P, j) { const size_t o8 = (size_t)(j)*8;                         \
        P##d = SL(o8 + 0); P##1 = SL(o8 + 1); P##2 = SL(o8 + 2);               \
        P##3 = SL(o8 + 3); P##4 = SL(o8 + 4); P##5 = SL(o8 + 5);               \
        P##6 = SL(o8 + 6); P##y = SL(o8 + 7); }
#define BSUB(P, j) {                                                           \
        const float rest = (P##6*x6 + P##5*x5) + (P##4*x4 + P##3*x3) + P##2*x2;\
        const float xr = ((P##y - rest) - P##1*x1) * P##d;                     \
        SX(j) = xr;                                                            \
        x6 = x5; x5 = x4; x4 = x3; x3 = x2; x2 = x1; x1 = xr; }
#define LOADSTEP(S, t) { LOAD8(S##C, 3*(t)+2) LOAD8(S##B, 3*(t)+1)             \
                         LOAD8(S##A, 3*(t)) }
#define BSUBSTEP(S, t) { BSUB(S##C, 3*(t)+2) BSUB(S##B, 3*(t)+1)               \
                         BSUB(S##A, 3*(t)) }

    float x1 = 0, x2 = 0, x3 = 0, x4 = 0, x5 = 0, x6 = 0;
    DECL8(PA) DECL8(PB) DECL8(PC)
    DECL8(QA) DECL8(QB) DECL8(QC)
    DECL8(RA) DECL8(RB) DECL8(RC)

    LOADSTEP(P, 63)
    LOADSTEP(Q, 62)
    LOADSTEP(R, 61)

    for (int t = 63; t >= 0; t -= 3) {
        BSUBSTEP(P, t)
        if (t - 3 >= 0) LOADSTEP(P, t - 3)
        if (t - 1 >= 0) {
            BSUBSTEP(Q, t - 1)
            if (t - 4 >= 0) LOADSTEP(Q, t - 4)
        }
        if (t - 2 >= 0) {
            BSUBSTEP(R, t - 2)
            if (t - 5 >= 0) LOADSTEP(R, t - 5)
        }
    }

#undef SLI
#undef SL
#undef SX
#undef CHOL_COL
#undef DECL8
#undef LOAD8
#undef BSUB
#undef LOADSTEP
#undef BSUBSTEP
}

// ============================================================================
// K3: transpose x from ws X-region to out. Coalesced both sides.
// ============================================================================
__global__ __launch_bounds__(1024, 1)
void ode_tout(const float* __restrict__ wsX, float* __restrict__ out)
{
    const int g   = blockIdx.x;
    const int tid = threadIdx.x;
    __shared__ float tile[64 * 193];

    for (int idx = tid; idx < NV * 64; idx += 1024) {
        const int j = idx >> 6, l = idx & 63;
        tile[l * 193 + j] = wsX[((size_t)g * X_SLOTS + j) * 64 + l];
    }
    __syncthreads();
    for (int idx = tid; idx < 64 * NV; idx += 1024) {
        const int b = idx / NV, j = idx - b * NV;
        out[(size_t)g * 64 * NV + idx] = tile[b * 193 + j];
    }
}

// ============================================================================
// Fallback A (round-3 fused kernel, known-pass): ws >= 6.3 MB only
// ============================================================================
__global__ __launch_bounds__(64, 1)
void ode_fused(const float* __restrict__ coeffs,
               const float* __restrict__ rhs,
               const float* __restrict__ iv_rhs,
               const float* __restrict__ steps,
               float* __restrict__ ws,
               float* __restrict__ out)
{
    const int g = blockIdx.x;
    const int l = threadIdx.x;
    const int b = (g << 6) | l;
    float* __restrict__ wsg = ws + (size_t)g * (NV * 8) * 64 + l;

#define SL(i) wsg[(size_t)(i) * 64]

    float W11 = 0, W12 = 0, W13 = 0, W14 = 0, W15 = 0, W16 = 0;
    float W22 = 0, W23 = 0, W24 = 0, W25 = 0, W26 = 0;
    float W33 = 0, W34 = 0, W35 = 0, W36 = 0;
    float W44 = 0, W45 = 0, W46 = 0;
    float W55 = 0, W56 = 0;
    float W66 = 0;
    float y1 = 0, y2 = 0, y3 = 0, y4 = 0, y5 = 0, y6 = 0;

#define CHOL_COL(j, b0, b1, b2, b3, b4, b5, b6, rvv)                           \
    {                                                                          \
        const float t0 = (b0) - (W11*W11 + W22*W22 + W33*W33 +                 \
                                 W44*W44 + W55*W55 + W66*W66);                 \
        const float dinv = rsqrtf(t0);                                         \
        const float u1 = (b1) - (W11*W12 + W22*W23 + W33*W34 +                 \
                                 W44*W45 + W55*W56);                           \
        const float u2 = (b2) - (W11*W13 + W22*W24 + W33*W35 + W44*W46);       \
        const float u3 = (b3) - (W11*W14 + W22*W25 + W33*W36);                 \
        const float u4 = (b4) - (W11*W15 + W22*W26);                           \
        const float u5 = (b5) - (W11*W16);                                     \
        const float u6 = (b6);                                                 \
        const float yj = ((rvv) - (W11*y1 + W22*y2 + W33*y3 +                  \
                                   W44*y4 + W55*y5 + W66*y6)) * dinv;          \
        const float n1 = u1*dinv, n2 = u2*dinv, n3 = u3*dinv;                  \
        const float n4 = u4*dinv, n5 = u5*dinv, n6 = u6*dinv;                  \
        SL((j)*8 + 0) = dinv; SL((j)*8 + 1) = n1;  SL((j)*8 + 2) = n2;         \
        SL((j)*8 + 3) = n3;   SL((j)*8 + 4) = n4;  SL((j)*8 + 5) = n5;         \
        SL((j)*8 + 6) = n6;   SL((j)*8 + 7) = yj;                              \
        W66 = W56;                                                             \
        W55 = W45; W56 = W46;                                                  \
        W44 = W34; W45 = W35; W46 = W36;                                       \
        W33 = W23; W34 = W24; W35 = W25; W36 = W26;                            \
        W22 = W12; W23 = W13; W24 = W14; W25 = W15; W26 = W16;                 \
        W11 = n1;  W12 = n2;  W13 = n3;  W14 = n4;  W15 = n5;  W16 = n6;       \
        y6 = y5; y5 = y4; y4 = y3; y3 = y2; y2 = y1; y1 = yj;                  \
    }

    const float iv00 = iv_rhs[(size_t)b*4 + 0];
    const float iv01 = iv_rhs[(size_t)b*4 + 1];
    const float iv10 = iv_rhs[(size_t)b*4 + 2];
    const float iv11 = iv_rhs[(size_t)b*4 + 3];

    float p  = 0.f;
    float s  = steps[(size_t)b*NT + 0];
    float sn = steps[(size_t)b*NT + 1];
    float c0 = coeffs[(size_t)b*NV + 0];
    float c1 = coeffs[(size_t)b*NV + 1];
    float c2 = coeffs[(size_t)b*NV + 2];
    float r  = rhs[(size_t)b*NS + 0];

    for (int t = 0; t < NS; ++t) {
        float nc0 = 0, nc1 = 0, nc2 = 0, nr = 0, ns2 = 0;
        if (t + 1 < NS) {
            const size_t cb = (size_t)b*NV + (size_t)(t + 1)*3;
            nc0 = coeffs[cb + 0];
            nc1 = coeffs[cb + 1];
            nc2 = coeffs[cb + 2];
            nr  = rhs[(size_t)b*NS + (t + 1)];
            if (t + 2 < NT) ns2 = steps[(size_t)b*NT + (t + 2)];
        }

        const float mS  = (t < NS - 1) ? 1.f : 0.f;
        const float mP  = (t >= 1)     ? 1.f : 0.f;
        const float mCN = (t < NS - 2) ? 1.f : 0.f;
        const float mC0 = (t >= 1 && t < NS - 1) ? 1.f : 0.f;
        const float rg  = (t < 2) ? 1.f : 0.f;
        const float ivA = (t == 0) ? iv00 : ((t == 1) ? iv10 : 0.f);
        const float ivB = (t == 0) ? iv01 : ((t == 1) ? iv11 : 0.f);

        const float s2 = s*s, s3 = s2*s, p2 = p*p, p3 = p2*p;
        const float gt = p + s;

        const float A0 = c0*c0 + rg + 2.f*(mS + mP);
        const float A1 = c0*c1 + s - p;
        const float A2 = c0*c2 + 0.5f*(s2 + p2);
        const float A3 = -2.f*mS;
        const float A4 = s;
        const float A5 = -0.5f*s2;

        const float B0 = c1*c1 + 3.f*(s2 + p2) + mCN + 1.f;
        const float B1 = c1*c2 + 1.5f*(s3 - p3);
        const float B2 = -s;
        const float B3 = -2.f*s2;
        const float B4 = s3 + (s + sn)*mCN;
        const float B6 = -mCN;

        const float Cv0 = c2*c2 + 1.25f*(s2*s2 + p2*p2) + gt*gt*mC0;
        const float Cv1 = -0.5f*s2;
        const float Cv2 = -s3 - gt*mC0;

        const float rv0 = c0*r + ivA;
        const float rv1 = c1*r + ivB;
        const float rv2 = c2*r;

        const int j0 = 3*t;
        CHOL_COL(j0 + 0, A0,  A1,  A2,  A3,  A4,  A5,  0.f, rv0);
        CHOL_COL(j0 + 1, B0,  B1,  B2,  B3,  B4,  0.f, B6,  rv1);
        CHOL_COL(j0 + 2, Cv0, Cv1, Cv2, 0.f, 0.f, 0.f, 0.f, rv2);

        p = s; s = sn; sn = ns2;
        c0 = nc0; c1 = nc1; c2 = nc2; r = nr;
    }

#define DECL8(P) float P##d = 0, P##1 = 0, P##2 = 0, P##3 = 0,                 \
                       P##4 = 0, P##5 = 0, P##6 = 0, P##y = 0;
#define LOAD8(P, j) { const size_t o8 = (size_t)(j)*8;                         \
        P##d = SL(o8 + 0); P##1 = SL(o8 + 1); P##2 = SL(o8 + 2);               \
        P##3 = SL(o8 + 3); P##4 = SL(o8 + 4); P##5 = SL(o8 + 5);               \
        P##6 = SL(o8 + 6); P##y = SL(o8 + 7); }
#define COPY8(D, S8) { D##d = S8##d; D##1 = S8##1; D##2 = S8##2;               \
        D##3 = S8##3; D##4 = S8##4; D##5 = S8##5; D##6 = S8##6; D##y = S8##y; }
#define BSUB(P, j) {                                                           \
        const float rest = (P##6*x6 + P##5*x5) + (P##4*x4 + P##3*x3) + P##2*x2;\
        const float xr = ((P##y - rest) - P##1*x1) * P##d;                     \
        out[(size_t)b*NV + (j)] = xr;                                          \
        x6 = x5; x5 = x4; x4 = x3; x3 = x2; x2 = x1; x1 = xr; }

    float x1 = 0, x2 = 0, x3 = 0, x4 = 0, x5 = 0, x6 = 0;
    DECL8(cC) DECL8(cB) DECL8(cA)
    DECL8(nC) DECL8(nB) DECL8(nA)

    LOAD8(cC, NV - 1)
    LOAD8(cB, NV - 2)
    LOAD8(cA, NV - 3)

    for (int t = NS - 1; t >= 0; --t) {
        if (t > 0) {
            const int jb = 3*(t - 1);
            LOAD8(nC, jb + 2)
            LOAD8(nB, jb + 1)
            LOAD8(nA, jb + 0)
        }
        const int j0 = 3*t;
        BSUB(cC, j0 + 2)
        BSUB(cB, j0 + 1)
        BSUB(cA, j0 + 0)
        COPY8(cC, nC) COPY8(cB, nB) COPY8(cA, nA)
    }

#undef SL
#undef CHOL_COL
#undef DECL8
#undef LOAD8
#undef COPY8
#undef BSUB
}

// ============================================================================
// Fallback B (round-1 kernel, known-pass): no ws requirement
// ============================================================================
__global__ __launch_bounds__(64, 1)
void ode_banded_solve(const float* __restrict__ coeffs,
                      const float* __restrict__ rhs,
                      const float* __restrict__ iv_rhs,
                      const float* __restrict__ steps,
                      float* __restrict__ out)
{
    const int b    = blockIdx.x;
    const int lane = threadIdx.x;

    __shared__ float band[NV * BW];
    __shared__ float rv[NV];
    __shared__ float stp[NT + 1];

    for (int i = lane; i < NV * BW; i += 64) band[i] = 0.0f;
    if (lane < NT) stp[lane] = steps[b * NT + lane];
    __syncthreads();

    {
        const int st = lane;
        const float c0 = coeffs[b * NV + st * 3 + 0];
        const float c1 = coeffs[b * NV + st * 3 + 1];
        const float c2 = coeffs[b * NV + st * 3 + 2];
        const float r  = rhs[b * NS + st];
        const float reg = (st < 2) ? 1.0f : 0.0f;
        atomicAdd(&band[(3 * st + 0) * BW + 0], c0 * c0 + reg);
        atomicAdd(&band[(3 * st + 1) * BW + 0], c1 * c1 + reg);
        atomicAdd(&band[(3 * st + 2) * BW + 0], c2 * c2);
        atomicAdd(&band[(3 * st + 1) * BW + 1], c1 * c0);
        atomicAdd(&band[(3 * st + 2) * BW + 1], c2 * c1);
        atomicAdd(&band[(3 * st + 2) * BW + 2], c2 * c0);
        float b0 = c0 * r, b1 = c1 * r, b2v = c2 * r;
        if (st < 2) {
            b0 += iv_rhs[b * 4 + st * 2 + 0];
            b1 += iv_rhs[b * 4 + st * 2 + 1];
        }
        rv[3 * st + 0] = b0;
        rv[3 * st + 1] = b1;
        rv[3 * st + 2] = b2v;
    }

    for (int t = lane; t < NC; t += 64) {
        int   cols[4];
        float vals[4];
        int   cnt;
        if (t < 126) {
            const int st = t >> 1, i = t & 1;
            const float s = stp[st];
            if (i == 0) {
                cols[0] = 3 * st + 0; vals[0] = 1.0f;
                cols[1] = 3 * st + 1; vals[1] = s;
                cols[2] = 3 * st + 2; vals[2] = 0.5f * s * s;
                cols[3] = 3 * st + 3; vals[3] = -1.0f;
                cnt = 4;
            } else {
                cols[0] = 3 * st + 1; vals[0] = s;
                cols[1] = 3 * st + 2; vals[1] = s * s;
                cols[2] = 3 * st + 4; vals[2] = -s;
                cnt = 3;
            }
        } else if (t < 188) {
            const int st = t - 126 + 1;
            const float cp = stp[st - 1] + stp[st];
            cols[0] = 3 * st - 2; vals[0] = -1.0f;
            cols[1] = 3 * st + 2; vals[1] = -cp;
            cols[2] = 3 * st + 4; vals[2] = 1.0f;
            cnt = 3;
        } else {
            const int tt = t - 188;
            const int st = tt >> 1, i = tt & 1;
            const float s = stp[st];
            if (i == 0) {
                cols[0] = 3 * st + 0; vals[0] = -1.0f;
                cols[1] = 3 * st + 3; vals[1] = 1.0f;
                cols[2] = 3 * st + 4; vals[2] = -s;
                cols[3] = 3 * st + 5; vals[3] = 0.5f * s * s;
                cnt = 4;
            } else {
                cols[0] = 3 * st + 1; vals[0] = s;
                cols[1] = 3 * st + 4; vals[1] = -s;
                cols[2] = 3 * st + 5; vals[2] = s * s;
                cnt = 3;
            }
        }
        for (int a = 0; a < cnt; ++a)
            for (int b2 = 0; b2 <= a; ++b2)
                atomicAdd(&band[cols[a] * BW + (cols[a] - cols[b2])],
                          vals[a] * vals[b2]);
    }
    __syncthreads();

    int pa = 0, pb = 0;
    {
        int idx = 0;
        for (int aa = 1; aa <= 6; ++aa)
            for (int bb = 1; bb <= aa; ++bb) {
                if (idx == lane) { pa = aa; pb = bb; }
                ++idx;
            }
    }
    const int sk = lane - 20;

    for (int j = 0; j < NV; ++j) {
        const int m = (NV - 1 - j < 6) ? (NV - 1 - j) : 6;
        const float diag = band[j * BW];
        const float d    = sqrtf(diag);
        const float dinv = 1.0f / d;

        const bool doU = (lane < 21) && (pa <= m);
        const bool doS = (lane >= 21) && (lane <= 26) && (sk <= m);
        float ca = 0.0f, cb = 0.0f, cs = 0.0f;
        if (doU) { ca = band[(j + pa) * BW + pa]; cb = band[(j + pb) * BW + pb]; }
        if (doS) { cs = band[(j + sk) * BW + sk]; }
        __syncthreads();

        if (lane == 0) band[j * BW] = d;
        if (doU) band[(j + pa) * BW + (pa - pb)] -= ca * cb * (dinv * dinv);
        if (doS) band[(j + sk) * BW + sk] = cs * dinv;
        __syncthreads();
    }

    for (int j = 0; j < NV; ++j) {
        const int m = (NV - 1 - j < 6) ? (NV - 1 - j) : 6;
        const float yj = rv[j] / band[j * BW];
        const bool doK = (lane >= 1) && (lane <= m);
        float sub = 0.0f, rj = 0.0f;
        if (doK) { sub = band[(j + lane) * BW + lane] * yj; rj = rv[j + lane]; }
        __syncthreads();
        if (lane == 0) rv[j] = yj;
        if (doK) rv[j + lane] = rj - sub;
        __syncthreads();
    }

    for (int j = NV - 1; j >= 0; --j) {
        const int m = (j < 6) ? j : 6;
        const float xj = rv[j] / band[j * BW];
        const bool doK = (lane >= 1) && (lane <= m);
        float sub = 0.0f, rj = 0.0f;
        if (doK) { sub = band[j * BW + lane] * xj; rj = rv[j - lane]; }
        __syncthreads();
        if (lane == 0) rv[j] = xj;
        if (doK) rv[j - lane] = rj - sub;
        __syncthreads();
    }

    for (int i = lane; i < NV; i += 64)
        out[b * NV + i] = rv[i];
}

extern "C" void kernel_launch(void* const* d_in, const int* in_sizes, int n_in,
                              void* d_out, int out_size, void* d_ws, size_t ws_size,
                              hipStream_t stream)
{
    const float* coeffs = (const float*)d_in[0];   // 1024*64*3
    const float* rhs    = (const float*)d_in[1];   // 1024*64
    const float* iv_rhs = (const float*)d_in[2];   // 1024*2*2
    const float* steps  = (const float*)d_in[3];   // 1024*63
    float* out = (float*)d_out;                    // 1024*192

    const size_t need2 = (size_t)(IN_SLOTS + L_SLOTS + X_SLOTS) * 64 * NG * sizeof(float); // ~8.4 MB
    const size_t need1 = (size_t)NG * (NV * 8) * 64 * sizeof(float);                       // ~6.3 MB

    if (ws_size >= need2) {
        float* wsIn = (float*)d_ws;
        float* wsL  = wsIn + (size_t)IN_SLOTS * 64 * NG;
        float* wsX  = wsL  + (size_t)L_SLOTS * 64 * NG;
        ode_tin<<<dim3(NG), dim3(1024), 0, stream>>>(coeffs, rhs, steps, iv_rhs, wsIn);
        ode_fused2<<<dim3(NG), dim3(64), 0, stream>>>(wsIn, wsL, wsX);
        ode_tout<<<dim3(NG), dim3(1024), 0, stream>>>(wsX, out);
    } else if (ws_size >= need1) {
        ode_fused<<<dim3(NG), dim3(64), 0, stream>>>(coeffs, rhs, iv_rhs, steps,
                                                     (float*)d_ws, out);
    } else {
        ode_banded_solve<<<dim3(NB), dim3(64), 0, stream>>>(coeffs, rhs, iv_rhs,
                                                            steps, out);
    }
}

// Round 5
// 61.023 us; speedup vs baseline: 1.1958x; 1.1958x over previous
//
#include <hip/hip_runtime.h>
#include <math.h>

// Problem constants (static config)
#define NB 1024     // batches
#define NS 64       // steps S
#define NT 63       // T = S-1
#define NV 192      // N = S*3 variables
#define BW 7        // band half-width+1 (fallback kernel)
#define NC 314      // constraint rows (fallback kernel)
#define NG 16       // 1024/64 wave-groups

// ws regions (per group, per lane): lane-transposed layout slot*64+lane
#define IN_SLOTS 328   // coeffs 0..191, rhs 192..255, steps 256..318, iv 320..323
#define L_SLOTS  1536  // 8 per column (dinv, L1..L6, y) x 192
#define X_SLOTS  192
#define IN_COEF 0
#define IN_RHS  192
#define IN_STP  256
#define IN_IV   320

// ============================================================================
// K1: transpose inputs into lane-transposed ws layout (coalesced both sides).
// ============================================================================
__global__ __launch_bounds__(1024, 1)
void ode_tin(const float* __restrict__ coeffs,
             const float* __restrict__ rhs,
             const float* __restrict__ steps,
             const float* __restrict__ iv_rhs,
             float* __restrict__ wsIn)
{
    const int g   = blockIdx.x;
    const int tid = threadIdx.x;
    __shared__ float tile[64 * 65];

    for (int c = 0; c < 3; ++c) {
        for (int idx = tid; idx < 64 * 64; idx += 1024) {
            const int b = idx >> 6, i = idx & 63;
            tile[b * 65 + i] = coeffs[(size_t)g * 12288 + (size_t)b * 192 + c * 64 + i];
        }
        __syncthreads();
        for (int idx = tid; idx < 64 * 64; idx += 1024) {
            const int i = idx >> 6, l = idx & 63;
            wsIn[((size_t)g * IN_SLOTS + IN_COEF + c * 64 + i) * 64 + l] = tile[l * 65 + i];
        }
        __syncthreads();
    }
    for (int idx = tid; idx < 64 * 64; idx += 1024) {
        const int b = idx >> 6, i = idx & 63;
        tile[b * 65 + i] = rhs[(size_t)g * 4096 + idx];
    }
    __syncthreads();
    for (int idx = tid; idx < 64 * 64; idx += 1024) {
        const int i = idx >> 6, l = idx & 63;
        wsIn[((size_t)g * IN_SLOTS + IN_RHS + i) * 64 + l] = tile[l * 65 + i];
    }
    __syncthreads();
    for (int idx = tid; idx < 64 * 63; idx += 1024) {
        const int b = idx / 63, i = idx - b * 63;
        tile[b * 65 + i] = steps[(size_t)g * 4032 + idx];
    }
    __syncthreads();
    for (int idx = tid; idx < 63 * 64; idx += 1024) {
        const int i = idx >> 6, l = idx & 63;
        wsIn[((size_t)g * IN_SLOTS + IN_STP + i) * 64 + l] = tile[l * 65 + i];
    }
    __syncthreads();
    for (int idx = tid; idx < 64 * 4; idx += 1024) {
        const int b = idx >> 2, i = idx & 3;
        tile[b * 65 + i] = iv_rhs[(size_t)g * 256 + idx];
    }
    __syncthreads();
    for (int idx = tid; idx < 4 * 64; idx += 1024) {
        const int i = idx >> 6, l = idx & 63;
        wsIn[((size_t)g * IN_SLOTS + IN_IV + i) * 64 + l] = tile[l * 65 + i];
    }
}

// ============================================================================
// K2: TWISTED factorization, one THREAD per batch, two independent chains:
//   fwd L-Cholesky cols 0..92 (steps 0..30, ascending)
//   bwd U-Cholesky cols 191..99 (steps 63..33, descending)
//   dense 6x6 middle block cols 93..98 from both register windows
// Fused forward solves (z) in both chains; back-substitution outward from the
// middle as two independent chains, unrolled x2 with static role swap.
// ============================================================================
__global__ __launch_bounds__(64, 1)
void ode_fused3(const float* __restrict__ wsIn,
                float* __restrict__ wsL,
                float* __restrict__ wsX)
{
    const int g = blockIdx.x;
    const int l = threadIdx.x;

    const float* __restrict__ inA = wsIn + (size_t)g * IN_SLOTS * 64 + l;
    float* __restrict__ lnA = wsL + (size_t)g * L_SLOTS * 64 + l;
    float* __restrict__ xA  = wsX + (size_t)g * X_SLOTS * 64 + l;

#define SLI(i) inA[(size_t)(i) * 64]
#define SL(i)  lnA[(size_t)(i) * 64]
#define SX(i)  xA[(size_t)(i) * 64]

// One twisted-Cholesky column (identical algebra fwd/bwd). W = window prefix,
// Y = z-window prefix. Stores (dinv, n1..n6, z_j) at col slot j.
#define CHOL_COL(W, Y, j, b0, b1, b2, b3, b4, b5, b6, rvv)                     \
    {                                                                          \
        const float t0_ = (b0) - (W##11*W##11 + W##22*W##22 + W##33*W##33 +    \
                                  W##44*W##44 + W##55*W##55 + W##66*W##66);    \
        const float di_ = rsqrtf(t0_);                                         \
        const float u1_ = (b1) - (W##11*W##12 + W##22*W##23 + W##33*W##34 +    \
                                  W##44*W##45 + W##55*W##56);                  \
        const float u2_ = (b2) - (W##11*W##13 + W##22*W##24 + W##33*W##35 +    \
                                  W##44*W##46);                                \
        const float u3_ = (b3) - (W##11*W##14 + W##22*W##25 + W##33*W##36);    \
        const float u4_ = (b4) - (W##11*W##15 + W##22*W##26);                  \
        const float u5_ = (b5) - (W##11*W##16);                                \
        const float u6_ = (b6);                                                \
        const float yj_ = ((rvv) - (W##11*Y##1 + W##22*Y##2 + W##33*Y##3 +     \
                                    W##44*Y##4 + W##55*Y##5 + W##66*Y##6))*di_;\
        const float n1_ = u1_*di_, n2_ = u2_*di_, n3_ = u3_*di_;               \
        const float n4_ = u4_*di_, n5_ = u5_*di_, n6_ = u6_*di_;               \
        SL((j)*8 + 0) = di_; SL((j)*8 + 1) = n1_; SL((j)*8 + 2) = n2_;         \
        SL((j)*8 + 3) = n3_; SL((j)*8 + 4) = n4_; SL((j)*8 + 5) = n5_;         \
        SL((j)*8 + 6) = n6_; SL((j)*8 + 7) = yj_;                              \
        W##66 = W##56;                                                         \
        W##55 = W##45; W##56 = W##46;                                          \
        W##44 = W##34; W##45 = W##35; W##46 = W##36;                           \
        W##33 = W##23; W##34 = W##24; W##35 = W##25; W##36 = W##26;            \
        W##22 = W##12; W##23 = W##13; W##24 = W##14; W##25 = W##15;            \
        W##26 = W##16;                                                         \
        W##11 = n1_; W##12 = n2_; W##13 = n3_; W##14 = n4_; W##15 = n5_;       \
        W##16 = n6_;                                                           \
        Y##6 = Y##5; Y##5 = Y##4; Y##4 = Y##3; Y##3 = Y##2; Y##2 = Y##1;       \
        Y##1 = yj_;                                                            \
    }

    // ---- fwd window (L) + z, bwd window (U) + z ----
    float W11=0,W12=0,W13=0,W14=0,W15=0,W16=0;
    float W22=0,W23=0,W24=0,W25=0,W26=0;
    float W33=0,W34=0,W35=0,W36=0;
    float W44=0,W45=0,W46=0;
    float W55=0,W56=0;
    float W66=0;
    float fy1=0,fy2=0,fy3=0,fy4=0,fy5=0,fy6=0;

    float V11=0,V12=0,V13=0,V14=0,V15=0,V16=0;
    float V22=0,V23=0,V24=0,V25=0,V26=0;
    float V33=0,V34=0,V35=0,V36=0;
    float V44=0,V45=0,V46=0;
    float V55=0,V56=0;
    float V66=0;
    float bz1=0,bz2=0,bz3=0,bz4=0,bz5=0,bz6=0;

    const float iv00 = SLI(IN_IV + 0);
    const float iv01 = SLI(IN_IV + 1);
    const float iv10 = SLI(IN_IV + 2);
    const float iv11 = SLI(IN_IV + 3);

    // fwd stream: step t (t=0..30): p=s_{t-1}, s=s_t, sn=s_{t+1}
    float fc0 = SLI(IN_COEF + 0), fc1 = SLI(IN_COEF + 1), fc2 = SLI(IN_COEF + 2);
    float fr  = SLI(IN_RHS + 0);
    float fp  = 0.f;
    float fs  = SLI(IN_STP + 0);
    float fsn = SLI(IN_STP + 1);

    // bwd stream: step bt (bt=63..33): s=s_bt (0 at bt=63), p=s_{bt-1}, pp=s_{bt-2}
    float bc0 = SLI(IN_COEF + 189), bc1 = SLI(IN_COEF + 190), bc2 = SLI(IN_COEF + 191);
    float brr = SLI(IN_RHS + 63);
    float bs  = 0.f;
    float bp  = SLI(IN_STP + 62);
    float bpp = SLI(IN_STP + 61);

    for (int t = 0; t <= 30; ++t) {
        const int bt = 63 - t;
        // ---- prefetch next step (both streams; all indices in-range) ----
        const float fc0n = SLI(IN_COEF + 3*(t+1) + 0);
        const float fc1n = SLI(IN_COEF + 3*(t+1) + 1);
        const float fc2n = SLI(IN_COEF + 3*(t+1) + 2);
        const float frn  = SLI(IN_RHS + t + 1);
        const float fsnn = SLI(IN_STP + t + 2);
        const float bc0n = SLI(IN_COEF + 3*(bt-1) + 0);
        const float bc1n = SLI(IN_COEF + 3*(bt-1) + 1);
        const float bc2n = SLI(IN_COEF + 3*(bt-1) + 2);
        const float brn  = SLI(IN_RHS + bt - 1);
        const float bppn = SLI(IN_STP + bt - 3);

        // ---- fwd column pieces for step t (t<=30: mS=mCN=1, mC0=mP) ----
        const float mP  = (t >= 1) ? 1.f : 0.f;
        const float rg  = (t < 2) ? 1.f : 0.f;
        const float ivA = (t == 0) ? iv00 : ((t == 1) ? iv10 : 0.f);
        const float ivB = (t == 0) ? iv01 : ((t == 1) ? iv11 : 0.f);
        const float fs2 = fs*fs, fs3 = fs2*fs, fp2 = fp*fp, fp3 = fp2*fp;
        const float fgt = fp + fs;
        const float A0 = fc0*fc0 + rg + 2.f*(1.f + mP);
        const float A1 = fc0*fc1 + fs - fp;
        const float A2 = fc0*fc2 + 0.5f*(fs2 + fp2);
        const float A4 = fs;
        const float A5 = -0.5f*fs2;
        const float B0 = fc1*fc1 + 3.f*(fs2 + fp2) + 2.f;
        const float B1 = fc1*fc2 + 1.5f*(fs3 - fp3);
        const float B2 = -fs;
        const float B3 = -2.f*fs2;
        const float B4 = fs3 + (fs + fsn);
        const float Cv0 = fc2*fc2 + 1.25f*(fs2*fs2 + fp2*fp2) + fgt*fgt*mP;
        const float Cv1 = -0.5f*fs2;
        const float Cv2 = -fs3 - fgt*mP;
        const float rv0 = fc0*fr + ivA;
        const float rv1 = fc1*fr + ivB;
        const float rv2 = fc2*fr;

        // ---- bwd column pieces for step bt (row-form band) ----
        const float mSb  = (bt < 63) ? 1.f : 0.f;
        const float mCNb = (bt < 62) ? 1.f : 0.f;
        const float mCNm = (bt < 63) ? 1.f : 0.f;   // mCN(bt-1)
        const float bs2 = bs*bs, bs3 = bs2*bs, bp2 = bp*bp, bp3 = bp2*bp;
        const float bgt = bp + bs;
        const float A0b = bc0*bc0 + 2.f*(mSb + 1.f);
        const float A1b = bc0*bc1 + bs - bp;
        const float A2b = bc0*bc2 + 0.5f*(bs2 + bp2);
        const float B0b = bc1*bc1 + 3.f*(bs2 + bp2) + mCNb + 1.f;
        const float B1b = bc1*bc2 + 1.5f*(bs3 - bp3);
        const float Cv0b = bc2*bc2 + 1.25f*(bs2*bs2 + bp2*bp2) + bgt*bgt*mSb;
        const float A4m = bp;
        const float A5m = -0.5f*bp2;
        const float B2m = -bp;
        const float B3m = -2.f*bp2;
        const float B4m = bp3 + (bp + bs)*mCNm;
        const float Cv1m = -0.5f*bp2;
        const float Cv2m = -bp3 - (bpp + bp);
        const float rv0b = bc0*brr;
        const float rv1b = bc1*brr;
        const float rv2b = bc2*brr;

        // ---- interleave the two independent chains ----
        const int j0 = 3*t, k0 = 3*bt;
        CHOL_COL(W, fy, j0 + 0, A0,  A1,  A2,  -2.f, A4,  A5,  0.f, rv0);
        CHOL_COL(V, bz, k0 + 2, Cv0b, B1b, A2b, 0.f, B4m, A5m, 0.f, rv2b);
        CHOL_COL(W, fy, j0 + 1, B0,  B1,  B2,  B3,  B4,  0.f, -1.f, rv1);
        CHOL_COL(V, bz, k0 + 1, B0b, A1b, Cv2m, B3m, A4m, 0.f, -1.f, rv1b);
        CHOL_COL(W, fy, j0 + 2, Cv0, Cv1, Cv2, 0.f, 0.f, 0.f, 0.f, rv2);
        CHOL_COL(V, bz, k0 + 0, A0b, Cv1m, B2m, -2.f, 0.f, 0.f, 0.f, rv0b);

        // ---- shift streams ----
        fp = fs; fs = fsn; fsn = fsnn;
        fc0 = fc0n; fc1 = fc1n; fc2 = fc2n; fr = frn;
        bs = bp; bp = bpp; bpp = bppn;
        bc0 = bc0n; bc1 = bc1n; bc2 = bc2n; brr = brn;
    }

    // ========================================================================
    // Middle block: cols 93..98 (steps 31 and 32), dense 6x6 SPD.
    // S[a][b] = M[93+a][93+b] - F(a,b) - G(a,b)
    //   F(a,b) = sum_{p=1..6-a} W[p][a+p]*W[p][b+p]   (fwd Schur)
    //   G(a,b) = sum_{p=1..b+1} V[p][p+5-a]*V[p][p+5-b] (bwd Schur)
    // ========================================================================
    {
        const float pA  = SLI(IN_STP + 30), sA = SLI(IN_STP + 31);
        const float snA = SLI(IN_STP + 32), sB = SLI(IN_STP + 32);
        const float pB  = sA,               snB = SLI(IN_STP + 33);
        const float c0A = SLI(IN_COEF + 93), c1A = SLI(IN_COEF + 94), c2A = SLI(IN_COEF + 95);
        const float c0B = SLI(IN_COEF + 96), c1B = SLI(IN_COEF + 97), c2B = SLI(IN_COEF + 98);
        const float rA  = SLI(IN_RHS + 31),  rB  = SLI(IN_RHS + 32);

        const float sA2 = sA*sA, sA3 = sA2*sA, pA2 = pA*pA, pA3 = pA2*pA;
        const float sB2 = sB*sB, sB3 = sB2*sB, pB2 = pB*pB, pB3 = pB2*pB;

        float S00 = c0A*c0A + 4.f;
        float S10 = c0A*c1A + sA - pA;
        float S20 = c0A*c2A + 0.5f*(sA2 + pA2);
        float S30 = -2.f;
        float S40 = sA;
        float S50 = -0.5f*sA2;
        float S11 = c1A*c1A + 3.f*(sA2 + pA2) + 2.f;
        float S21 = c1A*c2A + 1.5f*(sA3 - pA3);
        float S31 = -sA;
        float S41 = -2.f*sA2;
        float S51 = sA3 + (sA + snA);
        float S22 = c2A*c2A + 1.25f*(sA2*sA2 + pA2*pA2) + (pA + sA)*(pA + sA);
        float S32 = -0.5f*sA2;
        float S42 = -sA3 - (pA + sA);
        float S52 = 0.f;
        float S33 = c0B*c0B + 4.f;
        float S43 = c0B*c1B + sB - pB;
        float S53 = c0B*c2B + 0.5f*(sB2 + pB2);
        float S44 = c1B*c1B + 3.f*(sB2 + pB2) + 2.f;
        float S54 = c1B*c2B + 1.5f*(sB3 - pB3);
        float S55 = c2B*c2B + 1.25f*(sB2*sB2 + pB2*pB2) + (pB + sB)*(pB + sB);

        // subtract fwd Schur F(a,b)
        S00 -= W11*W11 + W22*W22 + W33*W33 + W44*W44 + W55*W55 + W66*W66;
        S10 -= W12*W11 + W23*W22 + W34*W33 + W45*W44 + W56*W55;
        S11 -= W12*W12 + W23*W23 + W34*W34 + W45*W45 + W56*W56;
        S20 -= W13*W11 + W24*W22 + W35*W33 + W46*W44;
        S21 -= W13*W12 + W24*W23 + W35*W34 + W46*W45;
        S22 -= W13*W13 + W24*W24 + W35*W35 + W46*W46;
        S30 -= W14*W11 + W25*W22 + W36*W33;
        S31 -= W14*W12 + W25*W23 + W36*W34;
        S32 -= W14*W13 + W25*W24 + W36*W35;
        S33 -= W14*W14 + W25*W25 + W36*W36;
        S40 -= W15*W11 + W26*W22;
        S41 -= W15*W12 + W26*W23;
        S42 -= W15*W13 + W26*W24;
        S43 -= W15*W14 + W26*W25;
        S44 -= W15*W15 + W26*W26;
        S50 -= W16*W11;
        S51 -= W16*W12;
        S52 -= W16*W13;
        S53 -= W16*W14;
        S54 -= W16*W15;
        S55 -= W16*W16;

        // subtract bwd Schur G(a,b)
        S00 -= V16*V16;
        S10 -= V15*V16;
        S11 -= V15*V15 + V26*V26;
        S20 -= V14*V16;
        S21 -= V14*V15 + V25*V26;
        S22 -= V14*V14 + V25*V25 + V36*V36;
        S30 -= V13*V16;
        S31 -= V13*V15 + V24*V26;
        S32 -= V13*V14 + V24*V25 + V35*V36;
        S33 -= V13*V13 + V24*V24 + V35*V35 + V46*V46;
        S40 -= V12*V16;
        S41 -= V12*V15 + V23*V26;
        S42 -= V12*V14 + V23*V25 + V34*V36;
        S43 -= V12*V13 + V23*V24 + V34*V35 + V45*V46;
        S44 -= V12*V12 + V23*V23 + V34*V34 + V45*V45 + V56*V56;
        S50 -= V11*V16;
        S51 -= V11*V15 + V22*V26;
        S52 -= V11*V14 + V22*V25 + V33*V36;
        S53 -= V11*V13 + V22*V24 + V33*V35 + V44*V46;
        S54 -= V11*V12 + V22*V23 + V33*V34 + V44*V45 + V55*V56;
        S55 -= V11*V11 + V22*V22 + V33*V33 + V44*V44 + V55*V55 + V66*V66;

        // rhs with both chains' z contributions
        float fm0 = c0A*rA - (W11*fy1 + W22*fy2 + W33*fy3 + W44*fy4 + W55*fy5 + W66*fy6)
                           - (V16*bz1);
        float fm1 = c1A*rA - (W12*fy1 + W23*fy2 + W34*fy3 + W45*fy4 + W56*fy5)
                           - (V15*bz1 + V26*bz2);
        float fm2 = c2A*rA - (W13*fy1 + W24*fy2 + W35*fy3 + W46*fy4)
                           - (V14*bz1 + V25*bz2 + V36*bz3);
        float fm3 = c0B*rB - (W14*fy1 + W25*fy2 + W36*fy3)
                           - (V13*bz1 + V24*bz2 + V35*bz3 + V46*bz4);
        float fm4 = c1B*rB - (W15*fy1 + W26*fy2)
                           - (V12*bz1 + V23*bz2 + V34*bz3 + V45*bz4 + V56*bz5);
        float fm5 = c2B*rB - (W16*fy1)
                           - (V11*bz1 + V22*bz2 + V33*bz3 + V44*bz4 + V55*bz5 + V66*bz6);

        // dense 6x6 Cholesky + fwd solve + back solve (static)
        const float md0 = rsqrtf(S00);
        const float M10 = S10*md0, M20 = S20*md0, M30 = S30*md0,
                    M40 = S40*md0, M50 = S50*md0;
        const float zm0 = fm0*md0;
        const float md1 = rsqrtf(S11 - M10*M10);
        const float M21 = (S21 - M20*M10)*md1;
        const float M31 = (S31 - M30*M10)*md1;
        const float M41 = (S41 - M40*M10)*md1;
        const float M51 = (S51 - M50*M10)*md1;
        const float zm1 = (fm1 - M10*zm0)*md1;
        const float md2 = rsqrtf(S22 - M20*M20 - M21*M21);
        const float M32 = (S32 - M30*M20 - M31*M21)*md2;
        const float M42 = (S42 - M40*M20 - M41*M21)*md2;
        const float M52 = (S52 - M50*M20 - M51*M21)*md2;
        const float zm2 = (fm2 - M20*zm0 - M21*zm1)*md2;
        const float md3 = rsqrtf(S33 - M30*M30 - M31*M31 - M32*M32);
        const float M43 = (S43 - M40*M30 - M41*M31 - M42*M32)*md3;
        const float M53 = (S53 - M50*M30 - M51*M31 - M52*M32)*md3;
        const float zm3 = (fm3 - M30*zm0 - M31*zm1 - M32*zm2)*md3;
        const float md4 = rsqrtf(S44 - M40*M40 - M41*M41 - M42*M42 - M43*M43);
        const float M54 = (S54 - M50*M40 - M51*M41 - M52*M42 - M53*M43)*md4;
        const float zm4 = (fm4 - M40*zm0 - M41*zm1 - M42*zm2 - M43*zm3)*md4;
        const float md5 = rsqrtf(S55 - M50*M50 - M51*M51 - M52*M52 - M53*M53 - M54*M54);
        const float zm5 = (fm5 - M50*zm0 - M51*zm1 - M52*zm2 - M53*zm3 - M54*zm4)*md5;

        const float xm5 = zm5*md5;
        const float xm4 = (zm4 - M54*xm5)*md4;
        const float xm3 = (zm3 - M43*xm4 - M53*xm5)*md3;
        const float xm2 = (zm2 - M32*xm3 - M42*xm4 - M52*xm5)*md2;
        const float xm1 = (zm1 - M21*xm2 - M31*xm3 - M41*xm4 - M51*xm5)*md1;
        const float xm0 = (zm0 - M10*xm1 - M20*xm2 - M30*xm3 - M40*xm4 - M50*xm5)*md0;

        SX(93) = xm0; SX(94) = xm1; SX(95) = xm2;
        SX(96) = xm3; SX(97) = xm4; SX(98) = xm5;

        // ====================================================================
        // Back-substitution: two independent chains outward from the middle.
        // top: cols 92..0 (steps 30..0); bottom: cols 99..191 (steps 33..63).
        // ====================================================================
#define DECL8(P) float P##d = 0, P##1 = 0, P##2 = 0, P##3 = 0,                 \
                       P##4 = 0, P##5 = 0, P##6 = 0, P##y = 0;
#define LOAD8(P, j) { const size_t o8 = (size_t)(j)*8;                         \
        P##d = SL(o8 + 0); P##1 = SL(o8 + 1); P##2 = SL(o8 + 2);               \
        P##3 = SL(o8 + 3); P##4 = SL(o8 + 4); P##5 = SL(o8 + 5);               \
        P##6 = SL(o8 + 6); P##y = SL(o8 + 7); }
#define BSUB_T(P, j) {                                                         \
        const float rest = (P##6*x6 + P##5*x5) + (P##4*x4 + P##3*x3) + P##2*x2;\
        const float xr = ((P##y - rest) - P##1*x1) * P##d;                     \
        SX(j) = xr;                                                            \
        x6 = x5; x5 = x4; x4 = x3; x3 = x2; x2 = x1; x1 = xr; }
#define BSUB_B(P, j) {                                                         \
        const float rest = (P##6*w6 + P##5*w5) + (P##4*w4 + P##3*w3) + P##2*w2;\
        const float xr = ((P##y - rest) - P##1*w1) * P##d;                     \
        SX(j) = xr;                                                            \
        w6 = w5; w5 = w4; w4 = w3; w3 = w2; w2 = w1; w1 = xr; }
// One joint iteration: prefetch next step both chains, then compute current.
#define BS_BODY(TCA,TCB,TCC, TNA,TNB,TNC, BCA,BCB,BCC, BNA,BNB,BNC, IT)        \
    {                                                                          \
        if ((IT) <= 29) {                                                      \
            const int tt = 29 - (IT);                                          \
            LOAD8(TNC, 3*tt + 2) LOAD8(TNB, 3*tt + 1) LOAD8(TNA, 3*tt)         \
            const int bb = 34 + (IT);                                          \
            LOAD8(BNA, 3*bb) LOAD8(BNB, 3*bb + 1) LOAD8(BNC, 3*bb + 2)         \
        }                                                                      \
        if ((IT) <= 30) {                                                      \
            const int ct = 30 - (IT);                                          \
            BSUB_T(TCC, 3*ct + 2) BSUB_T(TCB, 3*ct + 1) BSUB_T(TCA, 3*ct)      \
            const int cb = 33 + (IT);                                          \
            BSUB_B(BCA, 3*cb) BSUB_B(BCB, 3*cb + 1) BSUB_B(BCC, 3*cb + 2)      \
        }                                                                      \
    }

        float x1 = xm0, x2 = xm1, x3 = xm2, x4 = xm3, x5 = xm4, x6 = xm5;
        float w1 = xm5, w2 = xm4, w3 = xm3, w4 = xm2, w5 = xm1, w6 = xm0;

        DECL8(TPA) DECL8(TPB) DECL8(TPC) DECL8(TQA) DECL8(TQB) DECL8(TQC)
        DECL8(BPA) DECL8(BPB) DECL8(BPC) DECL8(BQA) DECL8(BQB) DECL8(BQC)

        LOAD8(TPC, 92) LOAD8(TPB, 91) LOAD8(TPA, 90)
        LOAD8(BPA, 99) LOAD8(BPB, 100) LOAD8(BPC, 101)

        for (int it = 0; it < 32; it += 2) {
            BS_BODY(TPA,TPB,TPC, TQA,TQB,TQC, BPA,BPB,BPC, BQA,BQB,BQC, it)
            BS_BODY(TQA,TQB,TQC, TPA,TPB,TPC, BQA,BQB,BQC, BPA,BPB,BPC, it + 1)
        }
    }

#undef SLI
#undef SL
#undef SX
#undef CHOL_COL
#undef DECL8
#undef LOAD8
#undef BSUB_T
#undef BSUB_B
#undef BS_BODY
}

// ============================================================================
// K3: transpose x from ws X-region to out. Coalesced both sides.
// ============================================================================
__global__ __launch_bounds__(1024, 1)
void ode_tout(const float* __restrict__ wsX, float* __restrict__ out)
{
    const int g   = blockIdx.x;
    const int tid = threadIdx.x;
    __shared__ float tile[64 * 193];

    for (int idx = tid; idx < NV * 64; idx += 1024) {
        const int j = idx >> 6, l = idx & 63;
        tile[l * 193 + j] = wsX[((size_t)g * X_SLOTS + j) * 64 + l];
    }
    __syncthreads();
    for (int idx = tid; idx < 64 * NV; idx += 1024) {
        const int b = idx / NV, j = idx - b * NV;
        out[(size_t)g * 64 * NV + idx] = tile[b * 193 + j];
    }
}

// ============================================================================
// Fallback (round-1 kernel, known-pass): used only if ws is too small
// ============================================================================
__global__ __launch_bounds__(64, 1)
void ode_banded_solve(const float* __restrict__ coeffs,
                      const float* __restrict__ rhs,
                      const float* __restrict__ iv_rhs,
                      const float* __restrict__ steps,
                      float* __restrict__ out)
{
    const int b    = blockIdx.x;
    const int lane = threadIdx.x;

    __shared__ float band[NV * BW];
    __shared__ float rv[NV];
    __shared__ float stp[NT + 1];

    for (int i = lane; i < NV * BW; i += 64) band[i] = 0.0f;
    if (lane < NT) stp[lane] = steps[b * NT + lane];
    __syncthreads();

    {
        const int st = lane;
        const float c0 = coeffs[b * NV + st * 3 + 0];
        const float c1 = coeffs[b * NV + st * 3 + 1];
        const float c2 = coeffs[b * NV + st * 3 + 2];
        const float r  = rhs[b * NS + st];
        const float reg = (st < 2) ? 1.0f : 0.0f;
        atomicAdd(&band[(3 * st + 0) * BW + 0], c0 * c0 + reg);
        atomicAdd(&band[(3 * st + 1) * BW + 0], c1 * c1 + reg);
        atomicAdd(&band[(3 * st + 2) * BW + 0], c2 * c2);
        atomicAdd(&band[(3 * st + 1) * BW + 1], c1 * c0);
        atomicAdd(&band[(3 * st + 2) * BW + 1], c2 * c1);
        atomicAdd(&band[(3 * st + 2) * BW + 2], c2 * c0);
        float b0 = c0 * r, b1 = c1 * r, b2v = c2 * r;
        if (st < 2) {
            b0 += iv_rhs[b * 4 + st * 2 + 0];
            b1 += iv_rhs[b * 4 + st * 2 + 1];
        }
        rv[3 * st + 0] = b0;
        rv[3 * st + 1] = b1;
        rv[3 * st + 2] = b2v;
    }

    for (int t = lane; t < NC; t += 64) {
        int   cols[4];
        float vals[4];
        int   cnt;
        if (t < 126) {
            const int st = t >> 1, i = t & 1;
            const float s = stp[st];
            if (i == 0) {
                cols[0] = 3 * st + 0; vals[0] = 1.0f;
                cols[1] = 3 * st + 1; vals[1] = s;
                cols[2] = 3 * st + 2; vals[2] = 0.5f * s * s;
                cols[3] = 3 * st + 3; vals[3] = -1.0f;
                cnt = 4;
            } else {
                cols[0] = 3 * st + 1; vals[0] = s;
                cols[1] = 3 * st + 2; vals[1] = s * s;
                cols[2] = 3 * st + 4; vals[2] = -s;
                cnt = 3;
            }
        } else if (t < 188) {
            const int st = t - 126 + 1;
            const float cp = stp[st - 1] + stp[st];
            cols[0] = 3 * st - 2; vals[0] = -1.0f;
            cols[1] = 3 * st + 2; vals[1] = -cp;
            cols[2] = 3 * st + 4; vals[2] = 1.0f;
            cnt = 3;
        } else {
            const int tt = t - 188;
            const int st = tt >> 1, i = tt & 1;
            const float s = stp[st];
            if (i == 0) {
                cols[0] = 3 * st + 0; vals[0] = -1.0f;
                cols[1] = 3 * st + 3; vals[1] = 1.0f;
                cols[2] = 3 * st + 4; vals[2] = -s;
                cols[3] = 3 * st + 5; vals[3] = 0.5f * s * s;
                cnt = 4;
            } else {
                cols[0] = 3 * st + 1; vals[0] = s;
                cols[1] = 3 * st + 4; vals[1] = -s;
                cols[2] = 3 * st + 5; vals[2] = s * s;
                cnt = 3;
            }
        }
        for (int a = 0; a < cnt; ++a)
            for (int b2 = 0; b2 <= a; ++b2)
                atomicAdd(&band[cols[a] * BW + (cols[a] - cols[b2])],
                          vals[a] * vals[b2]);
    }
    __syncthreads();

    int pa = 0, pb = 0;
    {
        int idx = 0;
        for (int aa = 1; aa <= 6; ++aa)
            for (int bb = 1; bb <= aa; ++bb) {
                if (idx == lane) { pa = aa; pb = bb; }
                ++idx;
            }
    }
    const int sk = lane - 20;

    for (int j = 0; j < NV; ++j) {
        const int m = (NV - 1 - j < 6) ? (NV - 1 - j) : 6;
        const float diag = band[j * BW];
        const float d    = sqrtf(diag);
        const float dinv = 1.0f / d;

        const bool doU = (lane < 21) && (pa <= m);
        const bool doS = (lane >= 21) && (lane <= 26) && (sk <= m);
        float ca = 0.0f, cb = 0.0f, cs = 0.0f;
        if (doU) { ca = band[(j + pa) * BW + pa]; cb = band[(j + pb) * BW + pb]; }
        if (doS) { cs = band[(j + sk) * BW + sk]; }
        __syncthreads();

        if (lane == 0) band[j * BW] = d;
        if (doU) band[(j + pa) * BW + (pa - pb)] -= ca * cb * (dinv * dinv);
        if (doS) band[(j + sk) * BW + sk] = cs * dinv;
        __syncthreads();
    }

    for (int j = 0; j < NV; ++j) {
        const int m = (NV - 1 - j < 6) ? (NV - 1 - j) : 6;
        const float yj = rv[j] / band[j * BW];
        const bool doK = (lane >= 1) && (lane <= m);
        float sub = 0.0f, rj = 0.0f;
        if (doK) { sub = band[(j + lane) * BW + lane] * yj; rj = rv[j + lane]; }
        __syncthreads();
        if (lane == 0) rv[j] = yj;
        if (doK) rv[j + lane] = rj - sub;
        __syncthreads();
    }

    for (int j = NV - 1; j >= 0; --j) {
        const int m = (j < 6) ? j : 6;
        const float xj = rv[j] / band[j * BW];
        const bool doK = (lane >= 1) && (lane <= m);
        float sub = 0.0f, rj = 0.0f;
        if (doK) { sub = band[j * BW + lane] * xj; rj = rv[j - lane]; }
        __syncthreads();
        if (lane == 0) rv[j] = xj;
        if (doK) rv[j - lane] = rj - sub;
        __syncthreads();
    }

    for (int i = lane; i < NV; i += 64)
        out[b * NV + i] = rv[i];
}

extern "C" void kernel_launch(void* const* d_in, const int* in_sizes, int n_in,
                              void* d_out, int out_size, void* d_ws, size_t ws_size,
                              hipStream_t stream)
{
    const float* coeffs = (const float*)d_in[0];   // 1024*64*3
    const float* rhs    = (const float*)d_in[1];   // 1024*64
    const float* iv_rhs = (const float*)d_in[2];   // 1024*2*2
    const float* steps  = (const float*)d_in[3];   // 1024*63
    float* out = (float*)d_out;                    // 1024*192

    const size_t need = (size_t)(IN_SLOTS + L_SLOTS + X_SLOTS) * 64 * NG * sizeof(float); // ~8.4 MB

    if (ws_size >= need) {
        float* wsIn = (float*)d_ws;
        float* wsL  = wsIn + (size_t)IN_SLOTS * 64 * NG;
        float* wsX  = wsL  + (size_t)L_SLOTS * 64 * NG;
        ode_tin<<<dim3(NG), dim3(1024), 0, stream>>>(coeffs, rhs, steps, iv_rhs, wsIn);
        ode_fused3<<<dim3(NG), dim3(64), 0, stream>>>(wsIn, wsL, wsX);
        ode_tout<<<dim3(NG), dim3(1024), 0, stream>>>(wsX, out);
    } else {
        ode_banded_solve<<<dim3(NB), dim3(64), 0, stream>>>(coeffs, rhs, iv_rhs,
                                                            steps, out);
    }
}